// Round 17
// baseline (43.101 us; speedup 1.0000x reference)
//
#include <hip/hip_runtime.h>
#include <hip/hip_bf16.h>

typedef short bfrag8 __attribute__((ext_vector_type(8)));
typedef float f32x4v __attribute__((ext_vector_type(4)));
typedef int i32x4 __attribute__((ext_vector_type(4)));
typedef unsigned short U16;
typedef unsigned int U32;

#define NN 4096
#define DD 128

static __device__ __forceinline__ U16 f2bf(float f){
  union { __hip_bfloat16 b; U16 u; } cv;
  cv.b = __float2bfloat16(f);
  return cv.u;
}

static __device__ __forceinline__ float bf2f(U32 u){
  union { float f; U32 u; } cv;
  cv.u = u << 16;
  return cv.f;
}

// i8 A-fragment (4 regs, 16 bytes of 0/1) from INVERTED adjacency bits.
static __device__ __forceinline__ i32x4 afragi8(U32 wl, U32 wh, int grp, U32 mul){
  U32 y = ((grp & 2) ? wh : wl) >> ((grp & 1) * 16);
  i32x4 a;
  a[0] = (int)((((y >>  0) & 0xFu) * mul) & 0x01010101u);
  a[1] = (int)((((y >>  4) & 0xFu) * mul) & 0x01010101u);
  a[2] = (int)((((y >>  8) & 0xFu) * mul) & 0x01010101u);
  a[3] = (int)((((y >> 12) & 0xFu) * mul) & 0x01010101u);
  return a;
}

// ---------------- kernel 0: adj pack TRANSPOSED+INVERTED (0..2047) + W^T ----------
__global__ __launch_bounds__(256) void k0_combo(const int* __restrict__ adj,
                                                U32* __restrict__ adjbT,
                                                const float* __restrict__ W,
                                                U16* __restrict__ WT){
  if (blockIdx.x >= 2048){
    int i = (blockIdx.x - 2048)*256 + threadIdx.x;  // i = d*128 + dp
    int d = i >> 7, dp = i & 127;
    WT[dp*128 + d] = f2bf(W[i]);
    return;
  }
  const int g   = blockIdx.x >> 4;                  // 0..127
  const int row = (blockIdx.x & 15)*256 + threadIdx.x;
  const int4* src = reinterpret_cast<const int4*>(adj + (size_t)row*NN + g*32);
  int4 v[8];
  #pragma unroll
  for (int c = 0; c < 8; ++c) v[c] = src[c];
  U32 m = 0;
  #pragma unroll
  for (int c = 0; c < 8; ++c){
    m |= (v[c].x != 0 ? 0u : 1u) << (c*4);
    m |= (v[c].y != 0 ? 0u : 2u) << (c*4);
    m |= (v[c].z != 0 ? 0u : 4u) << (c*4);
    m |= (v[c].w != 0 ? 0u : 8u) << (c*4);
  }
  adjbT[(size_t)g*4096 + row] = m;
}

// ---------------- kernel 1: 512 thr / 8 waves = 4 row-groups x 2 col-halves ------
// (frozen from R16) x2 = x*(nw+1)+nb; h = LN(x2@W); writes h_lnB + hTi8.
__global__ __launch_bounds__(512) void k1_prep(
    const float* __restrict__ x, const U16* __restrict__ WT,
    const float* __restrict__ nw, const float* __restrict__ nb,
    const float* __restrict__ gamma, const float* __restrict__ beta,
    U16* __restrict__ h_lnB, char* __restrict__ hTi8)
{
  __shared__ char smem[66560];               // 32K WT | 32K x-slab | 1K LN exchange
  U16* lds = reinterpret_cast<U16*>(smem);
  float4* xs4 = reinterpret_cast<float4*>(smem + 32768);
  float2* lnx = reinterpret_cast<float2*>(smem + 65536);   // [2 ch][64 rows]
  const int tid = threadIdx.x;
  const int lane = tid & 63, w = tid >> 6;
  const int rh = w >> 1, ch = w & 1;         // row-group (16 rows), col-half (64)
  const int l15 = lane & 15, grp = lane >> 4;

  #pragma unroll
  for (int q = 0; q < 4; ++q){
    int cid = q*512 + tid;
    int dp = cid >> 4, c = cid & 15;
    *reinterpret_cast<int4*>(lds + dp*128 + ((c*8) ^ ((dp&15)<<3))) =
        *reinterpret_cast<const int4*>(WT + cid*8);
  }
  {
    const float4* xg = reinterpret_cast<const float4*>(x) + (size_t)blockIdx.x*2048;
    #pragma unroll
    for (int k = 0; k < 4; ++k){
      int g = k*512 + tid;                   // 0..2047
      int row = g >> 5, c = g & 31;
      xs4[row*32 + ((c + row*2) & 31)] = xg[g];
    }
  }
  __syncthreads();

  const int rA = blockIdx.x*64 + rh*16 + l15;
  const int nA = rA & 4095;
  const float wgt = nw[nA] + 1.0f, bia = nb[nA];
  const int xrow = rh*16 + l15;              // row within slab

  f32x4v acc[4] = {};
  #pragma unroll
  for (int ks = 0; ks < 4; ++ks){
    int c0 = ks*8 + grp*2;
    float4 xa = xs4[xrow*32 + ((c0     + xrow*2) & 31)];
    float4 xb = xs4[xrow*32 + ((c0 + 1 + xrow*2) & 31)];
    bfrag8 af;
    af[0] = (short)f2bf(xa.x*wgt + bia);
    af[1] = (short)f2bf(xa.y*wgt + bia);
    af[2] = (short)f2bf(xa.z*wgt + bia);
    af[3] = (short)f2bf(xa.w*wgt + bia);
    af[4] = (short)f2bf(xb.x*wgt + bia);
    af[5] = (short)f2bf(xb.y*wgt + bia);
    af[6] = (short)f2bf(xb.z*wgt + bia);
    af[7] = (short)f2bf(xb.w*wgt + bia);
    #pragma unroll
    for (int nf = 0; nf < 4; ++nf){
      int dp = ch*64 + nf*16 + l15;
      bfrag8 bf = *reinterpret_cast<const bfrag8*>(
          lds + dp*128 + ((((ks*4 + grp)*8)) ^ ((dp&15)<<3)));
      acc[nf] = __builtin_amdgcn_mfma_f32_16x16x32_bf16(af, bf, acc[nf], 0, 0, 0);
    }
  }

  #pragma unroll
  for (int r = 0; r < 4; ++r){
    float s = 0.f, qq = 0.f;
    #pragma unroll
    for (int nf = 0; nf < 4; ++nf){ float v = acc[nf][r]; s += v; qq += v*v; }
    #pragma unroll
    for (int m = 1; m < 16; m <<= 1){ s += __shfl_xor(s, m); qq += __shfl_xor(qq, m); }
    if (l15 == 0) lnx[ch*64 + rh*16 + grp*4 + r] = make_float2(s, qq);
  }
  __syncthreads();

  float gc[4], bc[4];
  #pragma unroll
  for (int nf = 0; nf < 4; ++nf){
    int col = ch*64 + nf*16 + l15;
    gc[nf] = gamma[col]; bc[nf] = beta[col];
  }

  #pragma unroll
  for (int r = 0; r < 4; ++r){
    const int lrow = rh*16 + grp*4 + r;
    float2 pa = lnx[lrow], pb = lnx[64 + lrow];
    float s = pa.x + pb.x, qq = pa.y + pb.y;
    float mu = s * 0.0078125f;
    float var = fmaxf(qq*0.0078125f - mu*mu, 0.f);
    float rstd = rsqrtf(var + 1e-5f);
    const int rC = blockIdx.x*64 + lrow;
    #pragma unroll
    for (int nf = 0; nf < 4; ++nf){
      float hn = (acc[nf][r] - mu)*rstd*gc[nf] + bc[nf];
      acc[nf][r] = hn;
      h_lnB[(size_t)rC*DD + ch*64 + nf*16 + l15] = f2bf(hn);
    }
  }

  __syncthreads();   // reuse smem as hb[64 n][128 d] bf16
  #pragma unroll
  for (int r = 0; r < 4; ++r)
    #pragma unroll
    for (int nf = 0; nf < 4; ++nf)
      lds[(rh*16 + grp*4 + r)*128 + ch*64 + nf*16 + l15] = f2bf(acc[nf][r]);
  __syncthreads();

  {
    const int r0 = blockIdx.x*64;
    const int bB = r0 >> 12;
    const int nt = (r0 & 4095) >> 6;
    char* dstt = hTi8 + (((size_t)(bB*64 + nt)*128) << 6);
    const int d = tid & 127, q4 = tid >> 7;
    int pk[4];
    #pragma unroll
    for (int j = 0; j < 4; ++j){
      U32 word = 0;
      #pragma unroll
      for (int c = 0; c < 4; ++c){
        float v = bf2f((U32)lds[(q4*16 + j*4 + c)*128 + d]);
        float qf = fminf(fmaxf(rintf(v*32.f), -127.f), 127.f);
        int qi = (int)qf;
        word |= ((U32)(qi & 0xFF)) << (c*8);
      }
      pk[j] = (int)word;
    }
    int4 pa; pa.x = pk[0]; pa.y = pk[1]; pa.z = pk[2]; pa.w = pk[3];
    *reinterpret_cast<int4*>(dstt + (size_t)d*64 + q4*16) = pa;
  }
}

// ---------------- kernel 2: S = mask@h via i8 MFMA, N-split for 4 waves/SIMD ----
// 8 waves = 2 col-halves x 4 K-quarters; wave = 64 rows x 64 cols x K/4 ->
// acc[4][4] = 64 VGPR -> launch_bounds(512,4) -> 4 waves/SIMD, no B duplication.
// Double-banked reg prefetch, no main-loop barriers, 64 KB LDS i32 combine.
__global__ __launch_bounds__(512, 4) void k2_main(
    const U32* __restrict__ adjbT, const char* __restrict__ hTi8,
    const U16* __restrict__ h_lnB, float* __restrict__ out)
{
  __shared__ int part[16384];                // 64 KB: 2 regions x [64 r][128 c] i32
  const int tid = threadIdx.x;
  const int lane = tid & 63, w = tid >> 6;
  const int ch = w & 1, kq = w >> 1;         // col-half, K-quarter
  const int l15 = lane & 15, grp = lane >> 4;
  const int bid = blockIdx.x;
  const int xcd = bid & 7;
  const int b = xcd >> 1;                    // batch pinned to XCD pair
  const int iblk = (((bid >> 3) << 1) | (xcd & 1)) * 64;
  const float CM2 = 0.2f * -9.0e15f / 32.0f; // leaky(MASK_VAL) / quant scale
  const U32 MUL = 0x00204081u;

  // adj words g = kq*32 + 2s (+1), rows iblk + f*16 + l15 (f offsets fold into imm)
  const U32* ar = adjbT + (size_t)(kq*32)*4096 + iblk + l15;
  // B base: tile kq*16+s, col d = ch*64 + nf*16 + l15, k-bytes grp*16..
  const char* bp = hTi8 + (((size_t)(b*64 + kq*16)*128 + ch*64) << 6)
                   + l15*64 + grp*16;

  i32x4 acc[4][4] = {};

#define LOADB(P0,P1,P2,P3, S) do { \
    const char* _q = bp + (size_t)(S)*8192; \
    P0 = *reinterpret_cast<const i32x4*>(_q);        \
    P1 = *reinterpret_cast<const i32x4*>(_q + 1024); \
    P2 = *reinterpret_cast<const i32x4*>(_q + 2048); \
    P3 = *reinterpret_cast<const i32x4*>(_q + 3072); } while(0)

#define LOADW(L0,H0,L1,H1,L2,H2,L3,H3, S) do { \
    const U32* _a = ar + (size_t)(2*(S))*4096; \
    const U32* _b = ar + (size_t)(2*(S)+1)*4096; \
    L0 = _a[0];  H0 = _b[0]; \
    L1 = _a[16]; H1 = _b[16]; \
    L2 = _a[32]; H2 = _b[32]; \
    L3 = _a[48]; H3 = _b[48]; } while(0)

#define COLM(CF, NF) do { \
    acc[0][NF] = __builtin_amdgcn_mfma_i32_16x16x64_i8(a0, CF, acc[0][NF], 0,0,0); \
    acc[1][NF] = __builtin_amdgcn_mfma_i32_16x16x64_i8(a1, CF, acc[1][NF], 0,0,0); \
    acc[2][NF] = __builtin_amdgcn_mfma_i32_16x16x64_i8(a2, CF, acc[2][NF], 0,0,0); \
    acc[3][NF] = __builtin_amdgcn_mfma_i32_16x16x64_i8(a3, CF, acc[3][NF], 0,0,0); } while(0)

#define COMPUTE(P0,P1,P2,P3, L0,H0,L1,H1,L2,H2,L3,H3) do { \
    i32x4 a0 = afragi8(L0, H0, grp, MUL); \
    i32x4 a1 = afragi8(L1, H1, grp, MUL); \
    i32x4 a2 = afragi8(L2, H2, grp, MUL); \
    i32x4 a3 = afragi8(L3, H3, grp, MUL); \
    COLM(P0, 0); COLM(P1, 1); COLM(P2, 2); COLM(P3, 3); } while(0)

  i32x4 A0,A1,A2,A3, B0,B1,B2,B3;
  U32 aL0,aH0,aL1,aH1,aL2,aH2,aL3,aH3;
  U32 bL0,bH0,bL1,bH1,bL2,bH2,bL3,bH3;

  LOADB(A0,A1,A2,A3, 0);
  LOADW(aL0,aH0,aL1,aH1,aL2,aH2,aL3,aH3, 0);

  #pragma unroll 1
  for (int it = 0; it < 8; ++it){
    const int s = it*2;
    LOADB(B0,B1,B2,B3, s+1);
    LOADW(bL0,bH0,bL1,bH1,bL2,bH2,bL3,bH3, s+1);
    COMPUTE(A0,A1,A2,A3, aL0,aH0,aL1,aH1,aL2,aH2,aL3,aH3);
    LOADB(A0,A1,A2,A3, s+2);                 // s+2==16 on last iter: reads pad
    LOADW(aL0,aH0,aL1,aH1,aL2,aH2,aL3,aH3, s+2);
    COMPUTE(B0,B1,B2,B3, bL0,bH0,bL1,bH1,bL2,bH2,bL3,bH3);
  }

  // ---- exact i32 K-combine: 2 regions (64 KB); kq<2 write, kq>=2 RMW ----
  {
    int* reg = part + (kq & 1)*8192;
    if (kq < 2){
      #pragma unroll
      for (int f = 0; f < 4; ++f)
        #pragma unroll
        for (int nf = 0; nf < 4; ++nf){
          const int col = ch*64 + nf*16 + l15;
          #pragma unroll
          for (int r = 0; r < 4; ++r){
            const int lr = f*16 + grp*4 + r;
            reg[lr*128 + (col ^ (((lr>>2)&3)<<4))] = acc[f][nf][r];
          }
        }
    }
    __syncthreads();
    if (kq >= 2){
      #pragma unroll
      for (int f = 0; f < 4; ++f)
        #pragma unroll
        for (int nf = 0; nf < 4; ++nf){
          const int col = ch*64 + nf*16 + l15;
          #pragma unroll
          for (int r = 0; r < 4; ++r){
            const int lr = f*16 + grp*4 + r;
            const int idx = lr*128 + (col ^ (((lr>>2)&3)<<4));
            reg[idx] += acc[f][nf][r];
          }
        }
    }
    __syncthreads();
  }

  // ---- epilogue: 8 rows/wave, sum 2 regions, elu + residual ----
  #pragma unroll
  for (int rr = 0; rr < 8; ++rr){
    const int row = w*8 + rr;
    const int sw = ((row>>2)&3)<<4;
    const int idx = row*128 + ((2*lane) ^ sw);  // pair-safe: sw has no bit0
    int2 v0 = *reinterpret_cast<const int2*>(part + idx);
    int2 v1 = *reinterpret_cast<const int2*>(part + 8192 + idx);
    const int s0 = v0.x + v1.x, s1 = v0.y + v1.y;
    const float h0 = CM2 * (float)s0, h1 = CM2 * (float)s1;
    const float e0 = h0 > 0.f ? h0 : __expf(h0) - 1.f;
    const float e1 = h1 > 0.f ? h1 : __expf(h1) - 1.f;
    const size_t o = ((size_t)b*NN + iblk + row)*DD + 2*lane;
    const U32 hl = *reinterpret_cast<const U32*>(h_lnB + o);
    float2 ov; ov.x = e0 + bf2f(hl & 0xffffu); ov.y = e1 + bf2f(hl >> 16);
    *reinterpret_cast<float2*>(out + o) = ov;
  }
#undef COLM
#undef COMPUTE
#undef LOADW
#undef LOADB
}

extern "C" void kernel_launch(void* const* d_in, const int* in_sizes, int n_in,
                              void* d_out, int out_size, void* d_ws, size_t ws_size,
                              hipStream_t stream) {
  const float* x     = (const float*)d_in[0];
  const int*   adj   = (const int*)  d_in[1];
  const float* W     = (const float*)d_in[2];
  const float* nw    = (const float*)d_in[5];
  const float* nb    = (const float*)d_in[6];
  const float* gamma = (const float*)d_in[7];
  const float* beta  = (const float*)d_in[8];
  float* out = (float*)d_out;

  char* ws = (char*)d_ws;
  U16*  h_lnB = (U16*)(ws);                             // 4 MB
  char* hTi8  = (char*)(ws + 4*1024*1024);              // 2 MB + 64 KB pad
  U16*  WT    = (U16*)(ws + 6*1024*1024 + 64*1024);     // 32 KB
  U32*  adjbT = (U32*)(ws + 7*1024*1024);               // 2 MB + pad (ws is large)

  k0_combo<<<dim3(2112), dim3(256), 0, stream>>>(adj, adjbT, W, WT);
  k1_prep <<<dim3(256),  dim3(512), 0, stream>>>(x, WT, nw, nb, gamma, beta,
                                                 h_lnB, hTi8);
  k2_main <<<dim3(256),  dim3(512), 0, stream>>>(adjbT, hTi8, h_lnB, out);
}